// Round 3
// baseline (15220.528 us; speedup 1.0000x reference)
//
#include <hip/hip_runtime.h>
#include <stdint.h>

// ---------------------------------------------------------------------------
// 2-layer GRU, B=128, T=1024, H=IN=256, OUT=128.  Dtype probed on device.
//
// v8: MFMA rewrite.  v6/v7 counters proved the weight dwords live in AGPRs
// (allocator splits the unified file half arch/half acc at every budget) and
// each v_dot2 pays a v_accvgpr_read -> 2.5x VALU per dot, unfixable at HIP
// level.  MFMA reads AGPR operands natively, so the matrix path makes AGPR
// residency free AND moves the dots off the VALU pipe entirely.
//
// Structure: 8 groups x 16 batches, 4 roles (L0X,L0H,L1X,L1H) = 32 blocks
// x 512 threads (8 waves, 2/SIMD).  Per step each stage = (16x768x256)
// GEMM = 384 x mfma_f32_16x16x32_{bf16,f16} (~1860 clk/CU/step).  Wave w
// owns units [32w,32w+32): 3 gates x 2 unit-tiles x 8 k-frags = 48 B-frags
// (36 reg-resident, 12 in LDS).  h stays block-local in LDS (dbuf, chunk
// stride 17 uint4 to kill bank conflicts).  v6's proven ring protocol kept:
// 4-slot rings, in-band 8B {f16 sr,sz | f16 sn, tag16} relaxed atomics,
// progress counters, lgkm-only barrier.
// Frag layouts: D col=lane&15,row=4*(lane>>4)+i (m89-verified); A/B row =
// lane&15 of (A row-major / B^T row-major), 8 consecutive k at 8*(lane>>4).
// ---------------------------------------------------------------------------

#define XR0_OFF 0            // [8 grp][4 slot][8 wv][64 ln][8 j] u64 = 262144 dw
#define XR1_OFF 262144
#define HR_OFF  524288       // [8 grp][4 slot][16 m][256 u] u32   = 131072 dw
#define CTR_OFF 655360
#define FLG_OFF 659456

typedef _Float16 half8  __attribute__((ext_vector_type(8)));
typedef short    short8 __attribute__((ext_vector_type(8)));
typedef float    f32x4  __attribute__((ext_vector_type(4)));
typedef float    f4v    __attribute__((ext_vector_type(4)));
typedef _Float16 h2_t   __attribute__((ext_vector_type(2)));
union H2U { uint32_t u; h2_t h; };
union FU  { uint32_t u; float f; };

__device__ __forceinline__ float bf2f(uint16_t b){ FU v; v.u=(uint32_t)b<<16; return v.f; }
__device__ __forceinline__ uint16_t f2bf(float f){
    FU v; v.f=f; uint32_t r=v.u+0x7fffu+((v.u>>16)&1u); return (uint16_t)(r>>16);
}
__device__ __forceinline__ float rcp_f(float x){ return __builtin_amdgcn_rcpf(x); }
__device__ __forceinline__ float sigmoid_f(float x){ return rcp_f(1.0f+__expf(-x)); }
__device__ __forceinline__ float tanh_f(float x){
    float ax=fabsf(x); float e=__expf(-2.0f*ax);
    float t=(1.0f-e)*rcp_f(1.0f+e); return x<0.0f?-t:t;
}
__device__ __forceinline__ float hbits2f(uint32_t bits){
    H2U t; t.u = bits & 0xffffu; return (float)t.h[0];
}

#define RLX_LD(p)    __hip_atomic_load((p),        __ATOMIC_RELAXED, __HIP_MEMORY_SCOPE_AGENT)
#define RLX_ST(p,v)  __hip_atomic_store((p), (v),  __ATOMIC_RELAXED, __HIP_MEMORY_SCOPE_AGENT)
__device__ __forceinline__ uint64_t RLX_LD64(const uint64_t* p){
    return __hip_atomic_load(p, __ATOMIC_RELAXED, __HIP_MEMORY_SCOPE_AGENT);
}
__device__ __forceinline__ void RLX_ST64(uint64_t* p, uint64_t v){
    __hip_atomic_store(p, v, __ATOMIC_RELAXED, __HIP_MEMORY_SCOPE_AGENT);
}

// LDS-only barrier (ring publishes drain under compute; rings are tag-protected)
#define BAR() do {                                              \
    asm volatile("s_waitcnt lgkmcnt(0)" ::: "memory");          \
    __builtin_amdgcn_s_barrier();                               \
    asm volatile("" ::: "memory");                              \
} while (0)

template<bool BF>
__device__ __forceinline__ f32x4 MFMA16(uint4 a, uint4 b, f32x4 c){
    if constexpr (BF){
        short8 A = __builtin_bit_cast(short8, a);
        short8 Bv = __builtin_bit_cast(short8, b);
        return __builtin_amdgcn_mfma_f32_16x16x32_bf16(A, Bv, c, 0, 0, 0);
    } else {
        half8 A = __builtin_bit_cast(half8, a);
        half8 Bv = __builtin_bit_cast(half8, b);
        return __builtin_amdgcn_mfma_f32_16x16x32_f16(A, Bv, c, 0, 0, 0);
    }
}

// B-frag: 8 consecutive k of row `row` (row-major [768|128][256] weights)
template<bool BF>
__device__ __forceinline__ uint4 ldfragW(const void* W, int row, int k0){
    if constexpr (BF){
        return *((const uint4*)((const uint16_t*)W + (size_t)row*256 + k0));
    } else {
        const float* p = (const float*)W + (size_t)row*256 + k0;
        f4v f0 = *(const f4v*)p, f1 = *(const f4v*)(p+4);
        half8 h;
        h[0]=(_Float16)f0[0]; h[1]=(_Float16)f0[1]; h[2]=(_Float16)f0[2]; h[3]=(_Float16)f0[3];
        h[4]=(_Float16)f1[0]; h[5]=(_Float16)f1[1]; h[6]=(_Float16)f1[2]; h[7]=(_Float16)f1[3];
        return __builtin_bit_cast(uint4, h);
    }
}
template<bool BF>
__device__ __forceinline__ float ldbias(const void* b, int r){
    if constexpr (BF) return bf2f(((const uint16_t*)b)[r]);
    else              return ((const float*)b)[r];
}
template<bool BF>
__device__ __forceinline__ uint32_t hpack(float v){
    if constexpr (BF) return (uint32_t)f2bf(v);
    else { H2U t; t.u=0; t.h[0]=(_Float16)v; return t.u & 0xffffu; }
}

__global__ void probe_init(const uint32_t* __restrict__ w,
                           uint32_t* __restrict__ ctr,
                           uint32_t* __restrict__ flag) {
    int i = threadIdx.x;
    for (int k = i; k < 4096; k += 1024) ctr[k] = 0u;
    if (i == 0) {
        int c = 0;
        for (int j = 0; j < 64; ++j) {
            uint32_t e = (w[j] >> 7) & 0xFFu;
            c += (e >= 0x60u && e <= 0x7Cu) ? 1 : 0;
        }
        flag[0] = (c >= 32) ? 1u : 0u;
    }
}

// ---------------------------------------------------------------------------
// X stage, role 0: x(t) from global, staged via regs -> swizzled LDS dbuf.
// ---------------------------------------------------------------------------
template<bool BF>
__device__ __forceinline__ void xstage0(const void* xin, const void* Wx, const void* bx,
                                        uint32_t* ws, char* smem, int group, int tid)
{
    const int w = tid>>6, l = tid&63, l15 = l&15, lq = l>>4;
    uint4* wl = (uint4*)smem;
    char*  xb = smem + 98304;
    uint32_t* CTR = ws + CTR_OFF;
    uint32_t* myprg   = CTR + 0*1024 + group*16;
    uint32_t* consprg = CTR + 1*1024 + group*16;
    uint64_t* xrout = (uint64_t*)(ws + XR0_OFF) + (size_t)group*16384;

    uint4 breg[36];
#pragma unroll
    for (int f=0; f<48; ++f){
        int g = f>>4, u2 = (f>>3)&1, kk = f&7;
        uint4 bv = ldfragW<BF>(Wx, g*256 + 32*w + 16*u2 + l15, 32*kk + 8*lq);
        if (f < 36) breg[f] = bv; else wl[(f-36)*512 + tid] = bv;
    }
    float bias[6];
#pragma unroll
    for (int g=0; g<3; ++g)
#pragma unroll
        for (int u2=0; u2<2; ++u2)
            bias[g*2+u2] = ldbias<BF>(bx, g*256 + 32*w + 16*u2 + l15);

    // prologue fetch x(0)
    uint4 xr0, xr1;
    {
        if (BF){
            int b = tid>>5;
            xr0 = *(const uint4*)((const uint16_t*)xin + ((size_t)(group*16+b)*1024 + 0)*256 + (tid&31)*8);
        } else {
            int b = tid>>6;
            xr0 = *(const uint4*)((const float*)xin + ((size_t)(group*16+b)*1024 + 0)*256 + (tid&63)*4);
            xr1 = *(const uint4*)((const float*)xin + ((size_t)(group*16+b+8)*1024 + 0)*256 + (tid&63)*4);
        }
    }
    uint32_t prog_seen = 0;
    const int m_d0 = 4*lq;

    for (int t=0; t<1024; ++t){
        if (t >= 4 && prog_seen + 3 < (uint32_t)t){
            do { prog_seen = RLX_LD(consprg);
                 if (prog_seen + 3 < (uint32_t)t) __builtin_amdgcn_s_sleep(2);
            } while (prog_seen + 3 < (uint32_t)t);
        }
        // stage-write x(t) into buf[t&1] (swizzled rows)
        if (BF){
            int b = tid>>5, kb = (tid&31)*16;
            *(uint4*)(xb + (t&1)*8192 + b*512 + (kb ^ ((b&7)<<4))) = xr0;
        } else {
            int b = tid>>6, kb = (tid&63)*16;
            *(uint4*)(xb + (t&1)*16384 + b*1024 + (kb ^ ((b&7)<<4))) = xr0;
            int b2 = b+8;
            *(uint4*)(xb + (t&1)*16384 + b2*1024 + (kb ^ ((b2&7)<<4))) = xr1;
        }
        BAR();
        if (tid==0 && !(t&1)) RLX_ST(myprg, (uint32_t)t);
        if (t < 1023){
            if (BF){
                int b = tid>>5;
                xr0 = *(const uint4*)((const uint16_t*)xin + ((size_t)(group*16+b)*1024 + (t+1))*256 + (tid&31)*8);
            } else {
                int b = tid>>6;
                xr0 = *(const uint4*)((const float*)xin + ((size_t)(group*16+b)*1024 + (t+1))*256 + (tid&63)*4);
                xr1 = *(const uint4*)((const float*)xin + ((size_t)(group*16+b+8)*1024 + (t+1))*256 + (tid&63)*4);
            }
        }
        // A-frags from x_lds buf[t&1]
        uint4 afr[8];
#pragma unroll
        for (int kk=0; kk<8; ++kk){
            int k0 = 32*kk + 8*lq;
            if (BF){
                afr[kk] = *(const uint4*)(xb + (t&1)*8192 + l15*512 + ((k0*2) ^ ((l15&7)<<4)));
            } else {
                f4v f0 = *(const f4v*)(xb + (t&1)*16384 + l15*1024 + ((k0*4)    ^ ((l15&7)<<4)));
                f4v f1 = *(const f4v*)(xb + (t&1)*16384 + l15*1024 + ((k0*4+16) ^ ((l15&7)<<4)));
                half8 h;
                h[0]=(_Float16)f0[0]; h[1]=(_Float16)f0[1]; h[2]=(_Float16)f0[2]; h[3]=(_Float16)f0[3];
                h[4]=(_Float16)f1[0]; h[5]=(_Float16)f1[1]; h[6]=(_Float16)f1[2]; h[7]=(_Float16)f1[3];
                afr[kk] = __builtin_bit_cast(uint4, h);
            }
        }
        f32x4 acc[6];
#pragma unroll
        for (int i6=0;i6<6;++i6) acc[i6] = (f32x4){bias[i6],bias[i6],bias[i6],bias[i6]};
#pragma unroll
        for (int kk=0; kk<8; ++kk)
#pragma unroll
            for (int g=0; g<3; ++g)
#pragma unroll
                for (int u2=0; u2<2; ++u2){
                    int f = g*16 + u2*8 + kk;
                    uint4 bv = (f<36) ? breg[f] : wl[(f-36)*512 + tid];
                    acc[g*2+u2] = MFMA16<BF>(afr[kk], bv, acc[g*2+u2]);
                }
        // publish {f16 sr, f16 sz | f16 sn, tag16} x 8
        const uint32_t want = (uint32_t)(t+1);
#pragma unroll
        for (int u2=0; u2<2; ++u2)
#pragma unroll
            for (int i=0; i<4; ++i){
                int j = u2*4 + i;
                H2U lo; lo.h[0] = (_Float16)acc[0+u2][i]; lo.h[1] = (_Float16)acc[2+u2][i];
                H2U sn16; sn16.u = 0; sn16.h[0] = (_Float16)acc[4+u2][i];
                uint32_t hi = (sn16.u & 0xFFFFu) | (want << 16);
                RLX_ST64(xrout + ((size_t)(t&3)*512 + (size_t)w*64 + l)*8 + j,
                         (uint64_t)lo.u | ((uint64_t)hi << 32));
            }
        (void)m_d0;
    }
    BAR();
    if (tid==0) RLX_ST(myprg, 1024u);
}

// ---------------------------------------------------------------------------
// X stage, role 2: input = h0 from HR ring ({f16,tag16} per (m,u)), raw loads.
// ---------------------------------------------------------------------------
template<bool BF>
__device__ __forceinline__ void xstage1(const void* Wx, const void* bx,
                                        uint32_t* ws, char* smem, int group, int tid)
{
    const int w = tid>>6, l = tid&63, l15 = l&15, lq = l>>4;
    uint4* wl = (uint4*)smem;
    uint32_t* CTR = ws + CTR_OFF;
    uint32_t* myprg   = CTR + 2*1024 + group*16;
    uint32_t* consprg = CTR + 3*1024 + group*16;
    const uint64_t* hr64 = (const uint64_t*)(ws + HR_OFF + (size_t)group*16384);
    uint64_t* xrout = (uint64_t*)(ws + XR1_OFF) + (size_t)group*16384;

    uint4 breg[36];
#pragma unroll
    for (int f=0; f<48; ++f){
        int g = f>>4, u2 = (f>>3)&1, kk = f&7;
        uint4 bv = ldfragW<BF>(Wx, g*256 + 32*w + 16*u2 + l15, 32*kk + 8*lq);
        if (f < 36) breg[f] = bv; else wl[(f-36)*512 + tid] = bv;
    }
    float bias[6];
#pragma unroll
    for (int g=0; g<3; ++g)
#pragma unroll
        for (int u2=0; u2<2; ++u2)
            bias[g*2+u2] = ldbias<BF>(bx, g*256 + 32*w + 16*u2 + l15);

    uint64_t ph[16];
#pragma unroll
    for (int i=0;i<16;++i) ph[i]=0;
    uint32_t prog_seen = 0;

    for (int t=0; t<1024; ++t){
        if (t >= 4 && prog_seen + 3 < (uint32_t)t){
            do { prog_seen = RLX_LD(consprg);
                 if (prog_seen + 3 < (uint32_t)t) __builtin_amdgcn_s_sleep(2);
            } while (prog_seen + 3 < (uint32_t)t);
        }
        const uint32_t want = (uint32_t)(t+1) & 0xffffu;
        uint4 afr[8];
        // verify + assemble chunks 0..3 from prefetch
#pragma unroll
        for (int c=0; c<4; ++c){
            uint32_t dw[4];
#pragma unroll
            for (int q=0; q<4; ++q){
                uint64_t u = ph[c*4+q];
                const uint64_t* a = hr64 + ((size_t)(t&3)*16 + l15)*128 + 16*c + 4*lq + q;
                while ((((uint32_t)(u>>16) & 0xffffu) != want) || ((uint32_t)(u>>48) != want)){
                    __builtin_amdgcn_s_sleep(1);
                    u = RLX_LD64(a);
                }
                dw[q] = (uint32_t)(u & 0xffffu) | (((uint32_t)(u>>32) & 0xffffu) << 16);
            }
            afr[c] = (uint4){dw[0],dw[1],dw[2],dw[3]};
        }
        // issue loads for chunks 4..7
#pragma unroll
        for (int c=4; c<8; ++c)
#pragma unroll
            for (int q=0; q<4; ++q)
                ph[(c-4)*4+q] = RLX_LD64(hr64 + ((size_t)(t&3)*16 + l15)*128 + 16*c + 4*lq + q);
        BAR();
        if (tid==0 && !(t&1)) RLX_ST(myprg, (uint32_t)t);

        f32x4 acc[6];
#pragma unroll
        for (int i6=0;i6<6;++i6) acc[i6] = (f32x4){bias[i6],bias[i6],bias[i6],bias[i6]};
#pragma unroll
        for (int kk=0; kk<4; ++kk)
#pragma unroll
            for (int g=0; g<3; ++g)
#pragma unroll
                for (int u2=0; u2<2; ++u2){
                    int f = g*16 + u2*8 + kk;
                    uint4 bv = (f<36) ? breg[f] : wl[(f-36)*512 + tid];
                    acc[g*2+u2] = MFMA16<BF>(afr[kk], bv, acc[g*2+u2]);
                }
        // verify + assemble chunks 4..7
#pragma unroll
        for (int c=4; c<8; ++c){
            uint32_t dw[4];
#pragma unroll
            for (int q=0; q<4; ++q){
                uint64_t u = ph[(c-4)*4+q];
                const uint64_t* a = hr64 + ((size_t)(t&3)*16 + l15)*128 + 16*c + 4*lq + q;
                while ((((uint32_t)(u>>16) & 0xffffu) != want) || ((uint32_t)(u>>48) != want)){
                    __builtin_amdgcn_s_sleep(1);
                    u = RLX_LD64(a);
                }
                dw[q] = (uint32_t)(u & 0xffffu) | (((uint32_t)(u>>32) & 0xffffu) << 16);
            }
            afr[c] = (uint4){dw[0],dw[1],dw[2],dw[3]};
        }
#pragma unroll
        for (int kk=4; kk<8; ++kk)
#pragma unroll
            for (int g=0; g<3; ++g)
#pragma unroll
                for (int u2=0; u2<2; ++u2){
                    int f = g*16 + u2*8 + kk;
                    uint4 bv = (f<36) ? breg[f] : wl[(f-36)*512 + tid];
                    acc[g*2+u2] = MFMA16<BF>(afr[kk], bv, acc[g*2+u2]);
                }
        // publish
        const uint32_t wtag = (uint32_t)(t+1);
#pragma unroll
        for (int u2=0; u2<2; ++u2)
#pragma unroll
            for (int i=0; i<4; ++i){
                int j = u2*4 + i;
                H2U lo; lo.h[0] = (_Float16)acc[0+u2][i]; lo.h[1] = (_Float16)acc[2+u2][i];
                H2U sn16; sn16.u = 0; sn16.h[0] = (_Float16)acc[4+u2][i];
                uint32_t hi = (sn16.u & 0xFFFFu) | (wtag << 16);
                RLX_ST64(xrout + ((size_t)(t&3)*512 + (size_t)w*64 + l)*8 + j,
                         (uint64_t)lo.u | ((uint64_t)hi << 32));
            }
        // prefetch t+1 chunks 0..3
        if (t < 1023){
#pragma unroll
            for (int c=0; c<4; ++c)
#pragma unroll
                for (int q=0; q<4; ++q)
                    ph[c*4+q] = RLX_LD64(hr64 + ((size_t)((t+1)&3)*16 + l15)*128 + 16*c + 4*lq + q);
        }
    }
    BAR();
    if (tid==0) RLX_ST(myprg, 1024u);
}

// ---------------------------------------------------------------------------
// H stage (roles 1,3): consumes X-ring, h block-local in LDS dbuf.
// PUB: publish h to HR ring (role 1).  !PUB: out epilogue (role 3).
// ---------------------------------------------------------------------------
template<bool BF, bool PUB>
__device__ __forceinline__ void hstage(const void* Wh, const void* bh,
                                       const void* Wo, const void* bo, void* out,
                                       uint32_t* ws, char* smem, int group, int role, int tid)
{
    const int w = tid>>6, l = tid&63, l15 = l&15, lq = l>>4;
    uint4* wl = (uint4*)smem;
    uint32_t* hl32 = (uint32_t*)(smem + 98304);
    uint16_t* hl16 = (uint16_t*)(smem + 98304);
    uint4*    hl4  = (uint4*)(smem + 98304);
    uint32_t* CTR = ws + CTR_OFF;
    uint32_t* myprg   = CTR + role*1024 + group*16;
    uint32_t* consprg = CTR + (role+1)*1024 + group*16;
    const uint64_t* xr = (const uint64_t*)(ws + (role==1 ? XR0_OFF : XR1_OFF)) + (size_t)group*16384;
    uint32_t* hr = ws + HR_OFF + (size_t)group*16384;

    uint4 breg[36];
#pragma unroll
    for (int f=0; f<48; ++f){
        int g = f>>4, u2 = (f>>3)&1, kk = f&7;
        uint4 bv = ldfragW<BF>(Wh, g*256 + 32*w + 16*u2 + l15, 32*kk + 8*lq);
        if (f < 36) breg[f] = bv; else wl[(f-36)*512 + tid] = bv;
    }
    float bias[6];
#pragma unroll
    for (int g=0; g<3; ++g)
#pragma unroll
        for (int u2=0; u2<2; ++u2)
            bias[g*2+u2] = ldbias<BF>(bh, g*256 + 32*w + 16*u2 + l15);
    for (int i=tid; i<2176; i+=512) hl32[i] = 0u;     // h(0)=0, buf0

    float hreg[8];
#pragma unroll
    for (int j=0;j<8;++j) hreg[j]=0.f;
    uint64_t cur[8];
#pragma unroll
    for (int j=0;j<8;++j) cur[j]=0;
    uint32_t prog_seen = 0;
    const int m_d0 = 4*lq;

    for (int t=0; t<1024; ++t){
        if (PUB && t >= 4 && prog_seen + 3 < (uint32_t)t){
            do { prog_seen = RLX_LD(consprg);
                 if (prog_seen + 3 < (uint32_t)t) __builtin_amdgcn_s_sleep(2);
            } while (prog_seen + 3 < (uint32_t)t);
        }
        const uint32_t want = (uint32_t)(t+1);
#pragma unroll
        for (int j=0; j<8; ++j){
            if ((uint32_t)(cur[j]>>48) != want){
                const uint64_t* a = xr + ((size_t)(t&3)*512 + (size_t)w*64 + l)*8 + j;
                uint64_t u;
                do { u = RLX_LD64(a);
                     if ((uint32_t)(u>>48) != want) __builtin_amdgcn_s_sleep(1);
                } while ((uint32_t)(u>>48) != want);
                cur[j] = u;
            }
        }
        BAR();
        if (tid==0 && !(t&1)) RLX_ST(myprg, (uint32_t)t);
        // unpack s, then reuse cur[] for the t+1 prefetch
        float sr[8], sz[8], sn[8];
#pragma unroll
        for (int j=0; j<8; ++j){
            uint32_t loq = (uint32_t)cur[j];
            sr[j] = hbits2f(loq);
            sz[j] = hbits2f(loq >> 16);
            sn[j] = hbits2f((uint32_t)(cur[j]>>32));
        }
        if (t < 1023){
#pragma unroll
            for (int j=0; j<8; ++j)
                cur[j] = RLX_LD64(xr + ((size_t)((t+1)&3)*512 + (size_t)w*64 + l)*8 + j);
        }
        // A-frags from h_lds buf[t&1]
        uint4 afr[8];
        const int rb = (t&1)*544;
#pragma unroll
        for (int kk=0; kk<8; ++kk)
            afr[kk] = hl4[rb + (4*kk + lq)*17 + l15];
        f32x4 acc[6];
#pragma unroll
        for (int i6=0;i6<6;++i6) acc[i6] = (f32x4){bias[i6],bias[i6],bias[i6],bias[i6]};
#pragma unroll
        for (int kk=0; kk<8; ++kk)
#pragma unroll
            for (int g=0; g<3; ++g)
#pragma unroll
                for (int u2=0; u2<2; ++u2){
                    int f = g*16 + u2*8 + kk;
                    uint4 bv = (f<36) ? breg[f] : wl[(f-36)*512 + tid];
                    acc[g*2+u2] = MFMA16<BF>(afr[kk], bv, acc[g*2+u2]);
                }
        // epilogue: activations + h update + LDS write (+ ring publish)
        const int wb16 = (((t+1)&1)*544)*8;
#pragma unroll
        for (int u2=0; u2<2; ++u2){
            int u = 32*w + 16*u2 + l15;
            int chunkrow = u>>3;
#pragma unroll
            for (int i=0; i<4; ++i){
                int j = u2*4 + i;
                float r = sigmoid_f(sr[j] + acc[0+u2][i]);
                float z = sigmoid_f(sz[j] + acc[2+u2][i]);
                float n = tanh_f  (sn[j] + r*acc[4+u2][i]);
                float h = z*hreg[j] + (1.0f - z)*n;
                hreg[j] = h;
                uint32_t hb = hpack<BF>(h);
                int m_d = m_d0 + i;
                hl16[wb16 + chunkrow*136 + m_d*8 + (l15&7)] = (uint16_t)hb;
                if (PUB)
                    RLX_ST(hr + ((size_t)(t&3)*16 + m_d)*256 + u, hb | (want << 16));
            }
        }
    }
    BAR();
    if (tid==0) RLX_ST(myprg, 1024u);
    if (!PUB){
        // out = h1 @ Wo^T + bo   (h1 final lives in buf0: (1024&1)==0)
        uint4 afr[8];
#pragma unroll
        for (int kk=0; kk<8; ++kk)
            afr[kk] = hl4[(4*kk + lq)*17 + l15];
        int col = 16*w + l15;
        float bc = ldbias<BF>(bo, col);
        f32x4 acc = (f32x4){bc,bc,bc,bc};
#pragma unroll
        for (int kk=0; kk<8; ++kk){
            uint4 bv = ldfragW<BF>(Wo, col, 32*kk + 8*lq);
            acc = MFMA16<BF>(afr[kk], bv, acc);
        }
#pragma unroll
        for (int i=0; i<4; ++i){
            size_t oi = (size_t)(group*16 + m_d0 + i)*128 + col;
            if (BF) ((uint16_t*)out)[oi] = f2bf(acc[i]);
            else    ((float*)out)[oi]    = acc[i];
        }
    }
}

template<bool BF>
__device__ __forceinline__ void gru_body(
    const void* xin,
    const void* Wx0, const void* bx0, const void* Wh0, const void* bh0,
    const void* Wx1, const void* bx1, const void* Wh1, const void* bh1,
    const void* Wo,  const void* bo,  void* out, uint32_t* ws, char* smem)
{
    const int tid = threadIdx.x;
    const int group = blockIdx.x & 7;
    const int role  = blockIdx.x >> 3;
    if      (role == 0) xstage0<BF>(xin, Wx0, bx0, ws, smem, group, tid);
    else if (role == 1) hstage<BF, true >(Wh0, bh0, Wo, bo, out, ws, smem, group, 1, tid);
    else if (role == 2) xstage1<BF>(Wx1, bx1, ws, smem, group, tid);
    else                hstage<BF, false>(Wh1, bh1, Wo, bo, out, ws, smem, group, 3, tid);
}

__global__ void __launch_bounds__(512, 2)
gru9(const void* __restrict__ xin,
     const void* __restrict__ Wx0, const void* __restrict__ bx0,
     const void* __restrict__ Wh0, const void* __restrict__ bh0,
     const void* __restrict__ Wx1, const void* __restrict__ bx1,
     const void* __restrict__ Wh1, const void* __restrict__ bh1,
     const void* __restrict__ Wo,  const void* __restrict__ bo,
     void* __restrict__ out,
     uint32_t* __restrict__ ws)
{
    extern __shared__ char smem[];
    const int isbf = (int)ws[FLG_OFF];
    if (isbf) gru_body<true >(xin,Wx0,bx0,Wh0,bh0,Wx1,bx1,Wh1,bh1,Wo,bo,out,ws,smem);
    else      gru_body<false>(xin,Wx0,bx0,Wh0,bh0,Wx1,bx1,Wh1,bh1,Wo,bo,out,ws,smem);
}

extern "C" void kernel_launch(void* const* d_in, const int* in_sizes, int n_in,
                              void* d_out, int out_size, void* d_ws, size_t ws_size,
                              hipStream_t stream) {
    uint32_t* ws  = (uint32_t*)d_ws;
    uint32_t* CTR = ws + CTR_OFF;
    uint32_t* FLG = ws + FLG_OFF;

    static bool attr_done = false;
    if (!attr_done) {
        hipFuncSetAttribute(reinterpret_cast<const void*>(gru9),
                            hipFuncAttributeMaxDynamicSharedMemorySize, 131072);
        attr_done = true;
    }

    probe_init<<<dim3(1), dim3(1024), 0, stream>>>((const uint32_t*)d_in[1], CTR, FLG);
    gru9<<<dim3(32), dim3(512), 131072, stream>>>(
        d_in[0], d_in[1], d_in[2], d_in[3], d_in[4],
        d_in[5], d_in[6], d_in[7], d_in[8], d_in[9], d_in[10],
        d_out, ws);
}

// Round 4
// 2662.556 us; speedup vs baseline: 5.7165x; 5.7165x over previous
//
#include <hip/hip_runtime.h>
#include <stdint.h>

// ---------------------------------------------------------------------------
// 2-layer GRU, B=128, T=1024, H=IN=256, OUT=128.  Dtype probed on device.
//
// v9: v6 (best verified, 2719us) + ONLY the two micro-fixes that v7 bundled
// with its regressing structural change:
//  1) lgkm-only barrier: v6's __syncthreads() emits s_waitcnt vmcnt(0)
//     lgkmcnt(0), synchronously draining the just-issued ring-publish
//     atomic (~500-900cy MALL round trip) EVERY step.  Only LDS ordering
//     is required at this barrier (rings are tag-spin-protected), so use
//     asm lgkmcnt(0) + raw s_barrier.
//  2) v_rcp_f32 activations: 3 full-precision div chains/step (~30 VALU)
//     -> 3 v_rcp (error ~1ulp, far under the f16 ring quantization).
// Everything else byte-identical to v6: 256 blocks x 512 thr, roles
// L0X/L0H/L1X/L1H x 64 batch-pairs, weights register-resident, one
// barrier/step, skewed LDS, 4-slot rings with in-band 8B {payload,tag}
// relaxed-agent atomics, progress counters, waves_per_eu(2,2).
// (v8 post-mortem: MFMA+fine-grained atomic rings tripled HBM traffic and
//  spun on cross-XCD tags -> 15.2ms.  Ring protocol only works at v6's
//  one-publish-one-read-per-lane granularity.)
// ---------------------------------------------------------------------------

#define NPAIR 64

// ws layout in dwords
#define XR0_OFF 0            // uint2 [64][4][512]  (262144 dw)
#define XR1_OFF 262144       // uint2 [64][4][512]
#define HR0_OFF 524288       // uint2 [64][4][256]  (131072 dw)
#define CTR_OFF 655360       // u32   [4][64][16]
#define FLG_OFF 659456

#if defined(__has_builtin)
#if __has_builtin(__builtin_amdgcn_fdot2)
#define USE_DOT2 1
#endif
#if __has_builtin(__builtin_amdgcn_rcpf)
#define USE_RCP 1
#endif
#endif

typedef uint32_t u32x16 __attribute__((ext_vector_type(16)));
typedef _Float16 h2_t __attribute__((ext_vector_type(2)));
union H2U { uint32_t u; h2_t h; };
union FU  { uint32_t u; float f; };

__device__ __forceinline__ float bf2f(uint16_t b){ FU v; v.u=(uint32_t)b<<16; return v.f; }
__device__ __forceinline__ uint16_t f2bf(float f){
    FU v; v.f=f; uint32_t r=v.u+0x7fffu+((v.u>>16)&1u); return (uint16_t)(r>>16);
}
__device__ __forceinline__ float rcp_f(float x){
#ifdef USE_RCP
    return __builtin_amdgcn_rcpf(x);
#else
    return 1.0f/x;
#endif
}
__device__ __forceinline__ float sigmoid_f(float x){ return rcp_f(1.0f+__expf(-x)); }
__device__ __forceinline__ float tanh_f(float x){
    float ax=fabsf(x); float e=__expf(-2.0f*ax);
    float t=(1.0f-e)*rcp_f(1.0f+e); return x<0.0f?-t:t;
}
__device__ __forceinline__ float dot2acc(uint32_t w, uint32_t v, float acc){
#ifdef USE_DOT2
    H2U a,b; a.u=w; b.u=v;
    return __builtin_amdgcn_fdot2(a.h, b.h, acc, false);
#else
    FU x0,x1,y0,y1;
    x0.u=w<<16; x1.u=w&0xffff0000u; y0.u=v<<16; y1.u=v&0xffff0000u;
    acc=fmaf(x0.f,y0.f,acc); return fmaf(x1.f,y1.f,acc);
#endif
}
__device__ __forceinline__ uint32_t cvt_bfpair(uint32_t raw){
#ifdef USE_DOT2
    FU lo,hi; lo.u=raw<<16; hi.u=raw&0xffff0000u;
    H2U r; r.h[0]=(_Float16)lo.f; r.h[1]=(_Float16)hi.f; return r.u;
#else
    return raw;
#endif
}
__device__ __forceinline__ uint32_t packpair(float lo, float hi){
#ifdef USE_DOT2
    H2U r; r.h[0]=(_Float16)lo; r.h[1]=(_Float16)hi; return r.u;
#else
    return (uint32_t)f2bf(lo) | ((uint32_t)f2bf(hi)<<16);
#endif
}
__device__ __forceinline__ u32x16 load16_bf(const uint4* p){
    uint4 a=p[0], b=p[1], c=p[2], d=p[3];
    u32x16 v;
    v[0]=cvt_bfpair(a.x);  v[1]=cvt_bfpair(a.y);  v[2]=cvt_bfpair(a.z);  v[3]=cvt_bfpair(a.w);
    v[4]=cvt_bfpair(b.x);  v[5]=cvt_bfpair(b.y);  v[6]=cvt_bfpair(b.z);  v[7]=cvt_bfpair(b.w);
    v[8]=cvt_bfpair(c.x);  v[9]=cvt_bfpair(c.y);  v[10]=cvt_bfpair(c.z); v[11]=cvt_bfpair(c.w);
    v[12]=cvt_bfpair(d.x); v[13]=cvt_bfpair(d.y); v[14]=cvt_bfpair(d.z); v[15]=cvt_bfpair(d.w);
    return v;
}
__device__ __forceinline__ u32x16 load16_f32(const float2* p){
    u32x16 v;
#define LF(i) v[i] = packpair(p[i].x, p[i].y)
    LF(0);LF(1);LF(2);LF(3);LF(4);LF(5);LF(6);LF(7);
    LF(8);LF(9);LF(10);LF(11);LF(12);LF(13);LF(14);LF(15);
#undef LF
    return v;
}

#define RLX_LD(p)    __hip_atomic_load((p),        __ATOMIC_RELAXED, __HIP_MEMORY_SCOPE_AGENT)
#define RLX_ST(p,v)  __hip_atomic_store((p), (v),  __ATOMIC_RELAXED, __HIP_MEMORY_SCOPE_AGENT)
__device__ __forceinline__ uint64_t RLX_LD64(const uint64_t* p){
    return __hip_atomic_load(p, __ATOMIC_RELAXED, __HIP_MEMORY_SCOPE_AGENT);
}
__device__ __forceinline__ void RLX_ST64(uint64_t* p, uint64_t v){
    __hip_atomic_store(p, v, __ATOMIC_RELAXED, __HIP_MEMORY_SCOPE_AGENT);
}

// LDS-only barrier: order LDS (lgkmcnt) but do NOT drain vmcnt -> the 8B
// ring-publish atomics keep draining under the next dot loop.  The
// "memory"-clobber asms pin all memory ops on both sides of s_barrier.
#define BAR() do {                                              \
    asm volatile("s_waitcnt lgkmcnt(0)" ::: "memory");          \
    __builtin_amdgcn_s_barrier();                               \
    asm volatile("" ::: "memory");                              \
} while (0)

// 16 dwords of input (one quarter of this lane's half) vs 3 weight vecs
#define DOT16(WR, WZ, WN, G)                                                      \
    _Pragma("unroll")                                                             \
    for (int q = 0; q < 4; ++q) {                                                 \
        uint4 va = pa[4*(G)+q], vb = pb[4*(G)+q];                                 \
        ar0 = dot2acc(WR[4*q+0], va.x, ar0); ar1 = dot2acc(WR[4*q+0], vb.x, ar1); \
        az0 = dot2acc(WZ[4*q+0], va.x, az0); az1 = dot2acc(WZ[4*q+0], vb.x, az1); \
        an0 = dot2acc(WN[4*q+0], va.x, an0); an1 = dot2acc(WN[4*q+0], vb.x, an1); \
        ar0 = dot2acc(WR[4*q+1], va.y, ar0); ar1 = dot2acc(WR[4*q+1], vb.y, ar1); \
        az0 = dot2acc(WZ[4*q+1], va.y, az0); az1 = dot2acc(WZ[4*q+1], vb.y, az1); \
        an0 = dot2acc(WN[4*q+1], va.y, an0); an1 = dot2acc(WN[4*q+1], vb.y, an1); \
        ar0 = dot2acc(WR[4*q+2], va.z, ar0); ar1 = dot2acc(WR[4*q+2], vb.z, ar1); \
        az0 = dot2acc(WZ[4*q+2], va.z, az0); az1 = dot2acc(WZ[4*q+2], vb.z, az1); \
        an0 = dot2acc(WN[4*q+2], va.z, an0); an1 = dot2acc(WN[4*q+2], vb.z, an1); \
        ar0 = dot2acc(WR[4*q+3], va.w, ar0); ar1 = dot2acc(WR[4*q+3], vb.w, ar1); \
        az0 = dot2acc(WZ[4*q+3], va.w, az0); az1 = dot2acc(WZ[4*q+3], vb.w, az1); \
        an0 = dot2acc(WN[4*q+3], va.w, an0); an1 = dot2acc(WN[4*q+3], vb.w, an1); \
    }

__global__ void probe_init(const uint32_t* __restrict__ w,
                           uint32_t* __restrict__ ctr,
                           uint32_t* __restrict__ flag) {
    int i = threadIdx.x;
    for (int k = i; k < 4096; k += 1024) ctr[k] = 0u;
    if (i == 0) {
        int c = 0;
        for (int j = 0; j < 64; ++j) {
            uint32_t e = (w[j] >> 7) & 0xFFu;
            c += (e >= 0x60u && e <= 0x7Cu) ? 1 : 0;
        }
        flag[0] = (c >= 32) ? 1u : 0u;
    }
}

__global__ void __launch_bounds__(512) __attribute__((amdgpu_waves_per_eu(2, 2)))
gru10(const void* __restrict__ xin,
      const void* __restrict__ Wx0, const void* __restrict__ bx0,
      const void* __restrict__ Wh0, const void* __restrict__ bh0,
      const void* __restrict__ Wx1, const void* __restrict__ bx1,
      const void* __restrict__ Wh1, const void* __restrict__ bh1,
      const void* __restrict__ Wo,  const void* __restrict__ bo,
      void* __restrict__ out,
      uint32_t* __restrict__ ws)
{
    const int tid  = threadIdx.x;
    const int pair = blockIdx.x & (NPAIR - 1);
    const int role = blockIdx.x >> 6;
    const int p    = tid >> 1;       // hidden unit / row base
    const int hs   = tid & 1;        // column half (X) / batch index (H)

    uint64_t* XR0p = (uint64_t*)(ws + XR0_OFF) + pair * 2048;   // 4 slots x 512
    uint64_t* XR1p = (uint64_t*)(ws + XR1_OFF) + pair * 2048;
    uint64_t* HRp  = (uint64_t*)(ws + HR0_OFF) + pair * 1024;   // 4 slots x 256
    uint32_t* CTR  = ws + CTR_OFF;
    const int isbf = (int)ws[FLG_OFF];

    uint32_t* myprg   = CTR + role * 1024 + pair * 16;          // my staged step
    uint32_t* consprg = CTR + (role + 1) * 1024 + pair * 16;    // downstream's

    const void* Wsel; const void* bsel;
    if      (role == 0) { Wsel = Wx0; bsel = bx0; }
    else if (role == 1) { Wsel = Wh0; bsel = bh0; }
    else if (role == 2) { Wsel = Wx1; bsel = bx1; }
    else                { Wsel = Wh1; bsel = bh1; }

    // 12 named SSA weight vectors: half-rows of {p, p+256, p+512}
    u32x16 wr0,wr1,wr2,wr3, wz0,wz1,wz2,wz3, wn0,wn1,wn2,wn3;
    float br, bz, bn;
    if (isbf) {
        const uint4* W4 = (const uint4*)Wsel;
        const uint4* r0 = W4 + (size_t)p * 32 + hs * 16;
        const uint4* r1 = W4 + (size_t)(p + 256) * 32 + hs * 16;
        const uint4* r2 = W4 + (size_t)(p + 512) * 32 + hs * 16;
        wr0=load16_bf(r0);    wr1=load16_bf(r0+4);  wr2=load16_bf(r0+8);  wr3=load16_bf(r0+12);
        wz0=load16_bf(r1);    wz1=load16_bf(r1+4);  wz2=load16_bf(r1+8);  wz3=load16_bf(r1+12);
        wn0=load16_bf(r2);    wn1=load16_bf(r2+4);  wn2=load16_bf(r2+8);  wn3=load16_bf(r2+12);
        const uint16_t* bs = (const uint16_t*)bsel;
        br = bf2f(bs[p]); bz = bf2f(bs[p+256]); bn = bf2f(bs[p+512]);
    } else {
        const float2* W2 = (const float2*)Wsel;
        const float2* r0 = W2 + (size_t)p * 128 + hs * 64;
        const float2* r1 = W2 + (size_t)(p + 256) * 128 + hs * 64;
        const float2* r2 = W2 + (size_t)(p + 512) * 128 + hs * 64;
        wr0=load16_f32(r0);    wr1=load16_f32(r0+16); wr2=load16_f32(r0+32); wr3=load16_f32(r0+48);
        wz0=load16_f32(r1);    wz1=load16_f32(r1+16); wz2=load16_f32(r1+32); wz3=load16_f32(r1+48);
        wn0=load16_f32(r2);    wn1=load16_f32(r2+16); wn2=load16_f32(r2+32); wn3=load16_f32(r2+48);
        const float* bs = (const float*)bsel;
        br = bs[p]; bz = bs[p+256]; bn = bs[p+512];
    }

    // skewed LDS: 2 buffers x (2 x 136-dw halves); hs=1 half at +68 dwords
    __shared__ __align__(16) uint32_t sb[544];

    if (role == 0 || role == 2) {
        // ------------------------------ X stages ---------------------------
        const uint32_t* xs32 = (const uint32_t*)xin;
        const float2*   xsf  = (const float2*)xin;
        const int bglob = pair * 2 + (tid >> 7);
        const int i128  = tid & 127;
        const int spos  = (tid >> 7) * 136 + i128 + ((i128 >> 6) << 2);
        uint32_t xpref = 0;
        uint2 pfh; pfh.x = 0; pfh.y = 0;
        if (role == 0 && tid < 256) {
            if (isbf) xpref = cvt_bfpair(xs32[(size_t)bglob * 131072 + i128]);
            else { float2 f = xsf[(size_t)bglob * 131072 + i128]; xpref = packpair(f.x, f.y); }
        }
        uint64_t* outring = (role == 0) ? XR0p : XR1p;
        uint32_t prog_seen = 0;

        for (int t = 0; t < 1024; ++t) {
            if (t >= 4 && prog_seen + 3 < (uint32_t)t) {     // ring-wrap guard
                do { prog_seen = RLX_LD(consprg);
                     if (prog_seen + 3 < (uint32_t)t) __builtin_amdgcn_s_sleep(2);
                } while (prog_seen + 3 < (uint32_t)t);
            }
            if (tid < 256) {
                uint32_t pk;
                if (role == 0) pk = xpref;
                else {
                    uint2 v = pfh;
                    const uint32_t want = (uint32_t)(t + 1);
                    if (v.y != want) {
                        const uint64_t* a = HRp + (t & 3) * 256 + tid;
                        uint64_t u;
                        do { u = RLX_LD64(a);
                             v.x = (uint32_t)u; v.y = (uint32_t)(u >> 32);
                             if (v.y != want) __builtin_amdgcn_s_sleep(1);
                        } while (v.y != want);
                    }
                    pk = v.x;
                }
                sb[(t & 1) * 272 + spos] = pk;
            }
            BAR();
            if (tid == 0 && !(t & 1)) RLX_ST(myprg, (uint32_t)t);
            if (tid < 256 && t < 1023) {                     // prefetch t+1
                if (role == 0) {
                    if (isbf) xpref = cvt_bfpair(xs32[(size_t)bglob * 131072 + (t+1)*128 + i128]);
                    else { float2 f = xsf[(size_t)bglob * 131072 + (t+1)*128 + i128]; xpref = packpair(f.x, f.y); }
                } else {
                    uint64_t u = RLX_LD64(HRp + ((t + 1) & 3) * 256 + tid);
                    pfh.x = (uint32_t)u; pfh.y = (uint32_t)(u >> 32);
                }
            }
            float ar0=0,ar1=0,az0=0,az1=0,an0=0,an1=0;
            {
                const uint4* pa = ((const uint4*)&sb[(t & 1) * 272]) + hs * 17;
                const uint4* pb = pa + 34;
                DOT16(wr0,wz0,wn0,0); DOT16(wr1,wz1,wn1,1);
                DOT16(wr2,wz2,wn2,2); DOT16(wr3,wz3,wn3,3);
            }
            float R0 = ar0 + __shfl_xor(ar0,1), R1 = ar1 + __shfl_xor(ar1,1);
            float Z0 = az0 + __shfl_xor(az0,1), Z1 = az1 + __shfl_xor(az1,1);
            float N0 = an0 + __shfl_xor(an0,1), N1 = an1 + __shfl_xor(an1,1);
            float sr = (hs ? R1 : R0) + br;
            float sz = (hs ? Z1 : Z0) + bz;
            float sn = (hs ? N1 : N0) + bn;
            // publish {f16 sr, f16 sz | f16 sn, tag16} as one 8B atomic
            H2U lo; lo.h[0] = (_Float16)sr; lo.h[1] = (_Float16)sz;
            H2U sn16; sn16.u = 0; sn16.h[0] = (_Float16)sn;
            uint32_t hi = (sn16.u & 0xFFFFu) | (((uint32_t)(t + 1)) << 16);
            RLX_ST64(outring + (t & 3) * 512 + 2 * p + hs,
                     (uint64_t)lo.u | ((uint64_t)hi << 32));
        }
    } else {
        // ------------------------------ H stages ---------------------------
        const uint64_t* xr64 = (role == 1) ? XR0p : XR1p;
        float h_reg = 0.0f;
        for (int i = tid; i < 544; i += 512) sb[i] = 0u;   // h(0) = 0
        uint2 pfx; pfx.x = 0; pfx.y = 0;
        uint32_t prog_seen = 0;
        const int hj   = p >> 1;
        const int hpos = hs * 136 + hj + ((hj >> 6) << 2);

        for (int t = 0; t < 1024; ++t) {
            if (role == 1 && t >= 4 && prog_seen + 3 < (uint32_t)t) {
                do { prog_seen = RLX_LD(consprg);
                     if (prog_seen + 3 < (uint32_t)t) __builtin_amdgcn_s_sleep(2);
                } while (prog_seen + 3 < (uint32_t)t);
            }
            uint2 v = pfx;
            const uint32_t want = (uint32_t)(t + 1);
            if ((v.y >> 16) != want) {
                const uint64_t* a = xr64 + (t & 3) * 512 + 2 * p + hs;
                uint64_t u;
                do { u = RLX_LD64(a);
                     v.x = (uint32_t)u; v.y = (uint32_t)(u >> 32);
                     if ((v.y >> 16) != want) __builtin_amdgcn_s_sleep(1);
                } while ((v.y >> 16) != want);
            }
            H2U ua; ua.u = v.x;
            H2U ub; ub.u = v.y & 0xFFFFu;
            float xr = (float)ua.h[0], xz = (float)ua.h[1], xn = (float)ub.h[0];
            BAR();                           // h(t) LDS writes (prev iter) visible
            if (tid == 0 && !(t & 1)) RLX_ST(myprg, (uint32_t)t);
            if (t < 1023) {                  // prefetch t+1
                uint64_t u = RLX_LD64(xr64 + ((t + 1) & 3) * 512 + 2 * p + hs);
                pfx.x = (uint32_t)u; pfx.y = (uint32_t)(u >> 32);
            }
            float ar0=0,ar1=0,az0=0,az1=0,an0=0,an1=0;
            {
                const uint4* pa = ((const uint4*)&sb[(t & 1) * 272]) + hs * 17;
                const uint4* pb = pa + 34;
                DOT16(wr0,wz0,wn0,0); DOT16(wr1,wz1,wn1,1);
                DOT16(wr2,wz2,wn2,2); DOT16(wr3,wz3,wn3,3);
            }
            float R0 = ar0 + __shfl_xor(ar0,1), R1 = ar1 + __shfl_xor(ar1,1);
            float Z0 = az0 + __shfl_xor(az0,1), Z1 = az1 + __shfl_xor(az1,1);
            float N0 = an0 + __shfl_xor(an0,1), N1 = an1 + __shfl_xor(an1,1);
            float r = sigmoid_f(xr + (hs ? R1 : R0) + br);
            float z = sigmoid_f(xz + (hs ? Z1 : Z0) + bz);
            float n = tanh_f(xn + r * ((hs ? N1 : N0) + bn));
            h_reg = z * h_reg + (1.0f - z) * n;     // h[p], batch hs
            float hp = __shfl_xor(h_reg, 2);        // h[p^1], batch hs
            if (!(tid & 2)) {                       // p even: pack (h[p],h[p+1])
                uint32_t pk = packpair(h_reg, hp);
                sb[((t + 1) & 1) * 272 + hpos] = pk;
                if (role == 1)
                    RLX_ST64(HRp + (t & 3) * 256 + hs * 128 + hj,
                             (uint64_t)pk | ((uint64_t)(t + 1) << 32));
            }
        }
        BAR();
        if (tid == 0) RLX_ST(myprg, 1024u);

        // ---------------- epilogue (role 3): out = h1.Wo^T + bo ------------
        if (role == 3 && tid < 256) {
            const int j = tid >> 1, bb = tid & 1;
            const uint32_t* hv = &sb[bb * 136];     // final h1 in buffer 0
            float acc;
            if (isbf) {
                acc = bf2f(((const uint16_t*)bo)[j]);
                const uint32_t* wo = (const uint32_t*)Wo + j * 128;
#pragma unroll 8
                for (int c = 0; c < 128; ++c)
                    acc = dot2acc(cvt_bfpair(wo[c]), hv[c + ((c >> 6) << 2)], acc);
                ((uint16_t*)out)[(pair * 2 + bb) * 128 + j] = f2bf(acc);
            } else {
                acc = ((const float*)bo)[j];
                const float2* wo = (const float2*)Wo + j * 128;
#pragma unroll 8
                for (int c = 0; c < 128; ++c) {
                    float2 f = wo[c];
                    acc = dot2acc(packpair(f.x, f.y), hv[c + ((c >> 6) << 2)], acc);
                }
                ((float*)out)[(pair * 2 + bb) * 128 + j] = acc;
            }
        }
    }
}

extern "C" void kernel_launch(void* const* d_in, const int* in_sizes, int n_in,
                              void* d_out, int out_size, void* d_ws, size_t ws_size,
                              hipStream_t stream) {
    uint32_t* ws  = (uint32_t*)d_ws;
    uint32_t* CTR = ws + CTR_OFF;
    uint32_t* FLG = ws + FLG_OFF;

    probe_init<<<dim3(1), dim3(1024), 0, stream>>>((const uint32_t*)d_in[1], CTR, FLG);
    gru10<<<dim3(256), dim3(512), 0, stream>>>(
        d_in[0], d_in[1], d_in[2], d_in[3], d_in[4],
        d_in[5], d_in[6], d_in[7], d_in[8], d_in[9], d_in[10],
        d_out, ws);
}